// Round 12
// baseline (271.530 us; speedup 1.0000x reference)
//
#include <hip/hip_runtime.h>

#define IN_CH 512
#define SCAN_BLK 1024

typedef _Float16 f16x8 __attribute__((ext_vector_type(8)));
typedef float f32x4 __attribute__((ext_vector_type(4)));

// async global->LDS, 16B per lane. LDS dest is wave-uniform base + lane*16.
__device__ __forceinline__ void gload_lds16(const void* g, void* l) {
    __builtin_amdgcn_global_load_lds(
        (const __attribute__((address_space(1))) unsigned int*)g,
        (__attribute__((address_space(3))) unsigned int*)l, 16, 0, 0);
}

// ------- merged1: [0,DEGB) deg | [DEGB,DEGB+256) W1 cvt+transpose | rest cvt_x -------
// all three independent; deg's random atomics overlap the BW-bound cvt_x stream.
__global__ __launch_bounds__(256) void k_merged1(const int* __restrict__ col,
                                                 int* __restrict__ deg, int E, int N,
                                                 const float* __restrict__ W1,
                                                 _Float16* __restrict__ W1t,
                                                 const float* __restrict__ x,
                                                 _Float16* __restrict__ xh,
                                                 int degb, int total, int valid) {
    __shared__ float tile[32][33];
    const int bid = blockIdx.x;
    if (bid < degb) {
        int e = bid * 256 + threadIdx.x;
        if (e < E) {
            int d = col[e];
            if ((unsigned)d < (unsigned)N) atomicAdd(&deg[d], 1);
        }
        return;
    }
    if (bid < degb + 256) {
        const int b = bid - degb;
        const int bk = (b & 15) * 32, bn = (b >> 4) * 32;
        const int tx = threadIdx.x & 31, ty = threadIdx.x >> 5;   // 32 x 8
#pragma unroll
        for (int p = 0; p < 4; ++p)
            tile[ty + p * 8][tx] = W1[(size_t)(bk + ty + p * 8) * 512 + bn + tx];
        __syncthreads();
#pragma unroll
        for (int p = 0; p < 4; ++p)
            W1t[(size_t)(bn + ty + p * 8) * 512 + bk + tx] = (_Float16)tile[tx][ty + p * 8];
        return;
    }
    // ---- cvt_x: fp32 -> fp16, zero-pad to M2 rows ----
    int i = ((bid - degb - 256) * 256 + threadIdx.x) * 8;
    if (i >= total) return;
    f16x8 o;
    if (i < valid) {
        float4 v0 = *(const float4*)(x + i);
        float4 v1 = *(const float4*)(x + i + 4);
        o[0] = (_Float16)v0.x; o[1] = (_Float16)v0.y;
        o[2] = (_Float16)v0.z; o[3] = (_Float16)v0.w;
        o[4] = (_Float16)v1.x; o[5] = (_Float16)v1.y;
        o[6] = (_Float16)v1.z; o[7] = (_Float16)v1.w;
    } else {
        o = (f16x8)0;
    }
    *(f16x8*)(xh + i) = o;
}

// ---------------- scan pass 1: per-block sums ----------------
__global__ __launch_bounds__(SCAN_BLK) void k_psum(const int* __restrict__ deg,
                                                   int* __restrict__ bsum, int N) {
    __shared__ int red[SCAN_BLK / 64];
    int i = blockIdx.x * SCAN_BLK + threadIdx.x;
    int v = (i < N) ? deg[i] : 0;
#pragma unroll
    for (int off = 32; off > 0; off >>= 1) v += __shfl_down(v, off);
    if ((threadIdx.x & 63) == 0) red[threadIdx.x >> 6] = v;
    __syncthreads();
    if (threadIdx.x == 0) {
        int s = 0;
#pragma unroll
        for (int u = 0; u < SCAN_BLK / 64; ++u) s += red[u];
        bsum[blockIdx.x] = s;
    }
}

// ---- scan pass 2: per-block scan + block-offset reduce (gridDim <= 64) ----
__global__ __launch_bounds__(SCAN_BLK) void k_write(const int* __restrict__ deg,
                                                    const int* __restrict__ bsum,
                                                    int* __restrict__ rp,
                                                    float* __restrict__ dis,
                                                    int* __restrict__ cursor, int N) {
    __shared__ int sums[SCAN_BLK];
    __shared__ int boff_s, tot_s;
    int t = threadIdx.x;
    if (t < 64) {
        int v = (t < (int)gridDim.x) ? bsum[t] : 0;
        int pre = (t < (int)blockIdx.x) ? v : 0;
        int a = pre, b = v;
#pragma unroll
        for (int off = 32; off > 0; off >>= 1) {
            a += __shfl_down(a, off);
            b += __shfl_down(b, off);
        }
        if (t == 0) { boff_s = a; tot_s = b; }
    }
    int i = blockIdx.x * SCAN_BLK + t;
    int d = (i < N) ? deg[i] : 0;
    sums[t] = d;
    __syncthreads();
    for (int off = 1; off < SCAN_BLK; off <<= 1) {
        int u = (t >= off) ? sums[t - off] : 0;
        __syncthreads();
        sums[t] += u;
        __syncthreads();
    }
    if (i < N) {
        rp[i] = boff_s + sums[t] - d;   // exclusive prefix
        dis[i] = rsqrtf((float)d + 1.0f);
        cursor[i] = 0;
    }
    if (blockIdx.x == gridDim.x - 1 && t == 0) rp[N] = tot_s;
}

// ------- merged2: blocks [0,nwg) = fp16 MFMA GEMM, [nwg,nwg+fillb) = CSR fill -------
// GEMM first (long pole); fill's tiny latency-bound blocks backfill as gemm retires.
// Bank-conflict fix (R11: 9.6M 16-way conflicts): pre-swizzled global source keeps
// LDS linear for global_load_lds while the effective layout stores 16B chunk
// c^(row&7); ds_read uses the same involution -> 16-way becomes 2-way (free).
__global__ __launch_bounds__(256) void k_merged2(const _Float16* __restrict__ A,
                                                 const _Float16* __restrict__ Bt,
                                                 _Float16* __restrict__ C,
                                                 int nbm, int nwg,
                                                 const int* __restrict__ ei,
                                                 const int* __restrict__ rp,
                                                 int* __restrict__ cursor,
                                                 int* __restrict__ csrc,
                                                 int E, int N) {
    __shared__ __align__(16) _Float16 As[128 * 64];
    __shared__ __align__(16) _Float16 Bs[128 * 64];

    if ((int)blockIdx.x >= nwg) {
        int e = ((int)blockIdx.x - nwg) * 256 + threadIdx.x;
        if (e < E) {
            int s = ei[e];
            int d = ei[E + e];
            if ((unsigned)s < (unsigned)N && (unsigned)d < (unsigned)N) {
                int pos = atomicAdd(&cursor[d], 1);
                csrc[rp[d] + pos] = s;
            }
        }
        return;
    }

    // ---- GEMM: y = xh @ W1t^T (bn-fast + bijective XCD swizzle) ----
    const int g = (int)blockIdx.x;
    const int t = threadIdx.x;
    const int lane = t & 63, w = t >> 6;
    const int wm = w >> 1, wn = w & 1;

    const int q = nwg >> 3, r = nwg & 7;
    const int xcd = g & 7, within = g >> 3;
    const int wg = (xcd < r ? xcd * (q + 1) : r * (q + 1) + (xcd - r) * q) + within;
    const int bm = (wg >> 2) * 128, bn = (wg & 3) * 128;

    const int rr = lane & 15, kg = lane >> 4;
    const int lrow = lane >> 3;                            // staging row-in-8
    const int scol = ((lane & 7) ^ lrow) * 8;              // pre-swizzled source col
    const int rsw = rr & 7;                                // read-side row swizzle

    f32x4 acc[4][4];
#pragma unroll
    for (int i = 0; i < 4; ++i)
#pragma unroll
        for (int j = 0; j < 4; ++j) acc[i][j] = (f32x4)0.0f;

    for (int k0 = 0; k0 < 512; k0 += 64) {
#pragma unroll
        for (int p = 0; p < 4; ++p) {
            const int row = p * 32 + w * 8 + lrow;
            const int ldsbase = (p * 32 + w * 8) * 64;     // elements, wave-uniform
            gload_lds16(A + (size_t)(bm + row) * 512 + k0 + scol, As + ldsbase);
            gload_lds16(Bt + (size_t)(bn + row) * 512 + k0 + scol, Bs + ldsbase);
        }
        __syncthreads();
#pragma unroll
        for (int kk = 0; kk < 2; ++kk) {
            f16x8 a[4], b[4];
#pragma unroll
            for (int i = 0; i < 4; ++i)
                a[i] = *(const f16x8*)(As + (wm * 64 + i * 16 + rr) * 64 +
                                       (((kk << 2) + kg) ^ rsw) * 8);
#pragma unroll
            for (int j = 0; j < 4; ++j)
                b[j] = *(const f16x8*)(Bs + (wn * 64 + j * 16 + rr) * 64 +
                                       (((kk << 2) + kg) ^ rsw) * 8);
#pragma unroll
            for (int i = 0; i < 4; ++i)
#pragma unroll
                for (int j = 0; j < 4; ++j)
                    acc[i][j] = __builtin_amdgcn_mfma_f32_16x16x32_f16(a[i], b[j], acc[i][j], 0, 0, 0);
        }
        __syncthreads();
    }

    // C/D layout: col = lane&15, row = (lane>>4)*4 + reg
#pragma unroll
    for (int i = 0; i < 4; ++i)
#pragma unroll
        for (int j = 0; j < 4; ++j)
#pragma unroll
            for (int reg = 0; reg < 4; ++reg) {
                int m = bm + wm * 64 + i * 16 + kg * 4 + reg;
                int n = bn + wn * 64 + j * 16 + rr;
                C[(size_t)m * 512 + n] = (_Float16)acc[i][j][reg];
            }
}

// ---------------- layer-1 aggregation (R8 form: full width, unroll 8) ----------------
// R9/R10 lesson: channel-slicing cuts FETCH but time tracks slice count; R8's
// ~3.6 TB/s on the cross-L2 gather path is the practical floor. Do not touch.
__global__ __launch_bounds__(256) void k_agg(const _Float16* __restrict__ y,
                                             const float* __restrict__ dis,
                                             const int* __restrict__ rp,
                                             const int* __restrict__ csrc,
                                             const float* __restrict__ b1,
                                             const float* __restrict__ W2,
                                             float* __restrict__ z, int N) {
    const int n = blockIdx.x * 4 + (threadIdx.x >> 6);
    if (n >= N) return;
    const int l = threadIdx.x & 63;

    const float d1 = dis[n];
    f16x8 self = *(const f16x8*)(y + (size_t)n * 512 + l * 8);
    float acc[8];
#pragma unroll
    for (int c = 0; c < 8; ++c) acc[c] = d1 * (float)self[c];

    int j = rp[n], jend = rp[n + 1];
    for (; j + 8 <= jend; j += 8) {
        int s[8]; float wt[8]; f16x8 v[8];
#pragma unroll
        for (int u = 0; u < 8; ++u) s[u] = csrc[j + u];
#pragma unroll
        for (int u = 0; u < 8; ++u) wt[u] = dis[s[u]];
#pragma unroll
        for (int u = 0; u < 8; ++u)
            v[u] = *(const f16x8*)(y + (size_t)s[u] * 512 + l * 8);
#pragma unroll
        for (int u = 0; u < 8; ++u)
#pragma unroll
            for (int c = 0; c < 8; ++c) acc[c] += wt[u] * (float)v[u][c];
    }
    for (; j + 2 <= jend; j += 2) {
        int s0 = csrc[j], s1 = csrc[j + 1];
        float w0 = dis[s0], w1 = dis[s1];
        f16x8 v0 = *(const f16x8*)(y + (size_t)s0 * 512 + l * 8);
        f16x8 v1 = *(const f16x8*)(y + (size_t)s1 * 512 + l * 8);
#pragma unroll
        for (int c = 0; c < 8; ++c) acc[c] += w0 * (float)v0[c] + w1 * (float)v1[c];
    }
    if (j < jend) {
        int s0 = csrc[j];
        float w0 = dis[s0];
        f16x8 v0 = *(const f16x8*)(y + (size_t)s0 * 512 + l * 8);
#pragma unroll
        for (int c = 0; c < 8; ++c) acc[c] += w0 * (float)v0[c];
    }

    float4 bb0 = *(const float4*)(b1 + l * 8);
    float4 bb1 = *(const float4*)(b1 + l * 8 + 4);
    float4 w20 = *(const float4*)(W2 + l * 8);
    float4 w21 = *(const float4*)(W2 + l * 8 + 4);
    float bbv[8] = {bb0.x, bb0.y, bb0.z, bb0.w, bb1.x, bb1.y, bb1.z, bb1.w};
    float w2v[8] = {w20.x, w20.y, w20.z, w20.w, w21.x, w21.y, w21.z, w21.w};
    float p = 0.0f;
#pragma unroll
    for (int c = 0; c < 8; ++c) {
        float h = fmaxf(acc[c] * d1 + bbv[c], 0.0f);
        p += h * w2v[c];
    }
#pragma unroll
    for (int off = 32; off > 0; off >>= 1) p += __shfl_down(p, off);
    if (l == 0) z[n] = d1 * p;
}

// ---------------- layer-2 aggregation on prescaled scalars ----------------
__global__ void k_out(const float* __restrict__ z, const float* __restrict__ dis,
                      const int* __restrict__ rp, const int* __restrict__ csrc,
                      const float* __restrict__ b2, float* __restrict__ out, int N) {
    int n = blockIdx.x * blockDim.x + threadIdx.x;
    if (n >= N) return;
    float acc = z[n];
    int j = rp[n], jend = rp[n + 1];
    for (; j + 4 <= jend; j += 4) {
        float a0 = z[csrc[j]];
        float a1 = z[csrc[j + 1]];
        float a2 = z[csrc[j + 2]];
        float a3 = z[csrc[j + 3]];
        acc += (a0 + a1) + (a2 + a3);
    }
    for (; j < jend; ++j) acc += z[csrc[j]];
    out[n] = dis[n] * acc + b2[0];
}

extern "C" void kernel_launch(void* const* d_in, const int* in_sizes, int n_in,
                              void* d_out, int out_size, void* d_ws, size_t ws_size,
                              hipStream_t stream) {
    const float* x  = (const float*)d_in[0];
    const int*   ei = (const int*)d_in[1];
    const float* W1 = (const float*)d_in[2];
    const float* b1 = (const float*)d_in[3];
    const float* W2 = (const float*)d_in[4];
    const float* b2 = (const float*)d_in[5];
    float* out = (float*)d_out;

    const int N = in_sizes[0] / IN_CH;            // 50000
    const int E = in_sizes[1] / 2;                // 800000
    const int nbm = (N + 127) / 128;              // 391
    const int M2 = nbm * 128;                     // 50048
    const int NB = (N + SCAN_BLK - 1) / SCAN_BLK; // 49 (<= 64 for k_write)
    const int DEGB = (E + 255) / 256;             // 3125
    const int CVTB = (M2 * 512) / 2048;           // 12512
    const int nwg  = nbm * 4;                     // 1564

    char* ws = (char*)d_ws;
    size_t off = 0;
    auto alloc = [&](size_t bytes) {
        char* p = ws + off;
        off += (bytes + 255) & ~(size_t)255;
        return p;
    };
    _Float16* xh  = (_Float16*)alloc((size_t)M2 * 512 * sizeof(_Float16)); // 51.25 MB
    _Float16* y   = (_Float16*)alloc((size_t)M2 * 512 * sizeof(_Float16)); // 51.25 MB
    _Float16* W1t = (_Float16*)alloc((size_t)512 * 512 * sizeof(_Float16));
    int*   deg    = (int*)alloc((size_t)N * sizeof(int));
    float* dis    = (float*)alloc((size_t)N * sizeof(float));
    int*   rp     = (int*)alloc((size_t)(N + 1) * sizeof(int));
    int*   cursor = (int*)alloc((size_t)N * sizeof(int));
    int*   csrc   = (int*)alloc((size_t)E * sizeof(int));
    float* z      = (float*)alloc((size_t)N * sizeof(float));
    int*   bsum   = (int*)alloc((size_t)64 * sizeof(int));

    hipMemsetAsync(deg, 0, (size_t)N * sizeof(int), stream);

    k_merged1<<<DEGB + 256 + CVTB, 256, 0, stream>>>(ei + E, deg, E, N,
                                                     W1, W1t, x, xh,
                                                     DEGB, M2 * 512, N * 512);
    k_psum<<<NB, SCAN_BLK, 0, stream>>>(deg, bsum, N);
    k_write<<<NB, SCAN_BLK, 0, stream>>>(deg, bsum, rp, dis, cursor, N);
    k_merged2<<<nwg + DEGB, 256, 0, stream>>>(xh, W1t, y, nbm, nwg,
                                              ei, rp, cursor, csrc, E, N);
    k_agg<<<(N + 3) / 4, 256, 0, stream>>>(y, dis, rp, csrc, b1, W2, z, N);
    k_out<<<(N + 255) / 256, 256, 0, stream>>>(z, dis, rp, csrc, b2, out, N);
}

// Round 13
// 250.976 us; speedup vs baseline: 1.0819x; 1.0819x over previous
//
#include <hip/hip_runtime.h>

#define IN_CH 512
#define SCAN_BLK 1024

typedef _Float16 f16x8 __attribute__((ext_vector_type(8)));
typedef float f32x4 __attribute__((ext_vector_type(4)));

// async global->LDS, 16B per lane. LDS dest is wave-uniform base + lane*16.
__device__ __forceinline__ void gload_lds16(const void* g, void* l) {
    __builtin_amdgcn_global_load_lds(
        (const __attribute__((address_space(1))) unsigned int*)g,
        (__attribute__((address_space(3))) unsigned int*)l, 16, 0, 0);
}

// ------- merged1: blocks [0,256) = W1 cvt+transpose, rest = degree count -------
__global__ __launch_bounds__(256) void k_merged1(const float* __restrict__ W1,
                                                 _Float16* __restrict__ W1t,
                                                 const int* __restrict__ col,
                                                 int* __restrict__ deg, int E, int N) {
    __shared__ float tile[32][33];
    if ((int)blockIdx.x >= 256) {
        int e = ((int)blockIdx.x - 256) * 256 + threadIdx.x;
        if (e < E) {
            int d = col[e];
            if ((unsigned)d < (unsigned)N) atomicAdd(&deg[d], 1);
        }
        return;
    }
    const int bk = (blockIdx.x & 15) * 32, bn = (blockIdx.x >> 4) * 32;
    const int tx = threadIdx.x & 31, ty = threadIdx.x >> 5;   // 32 x 8
#pragma unroll
    for (int p = 0; p < 4; ++p)
        tile[ty + p * 8][tx] = W1[(size_t)(bk + ty + p * 8) * 512 + bn + tx];
    __syncthreads();
#pragma unroll
    for (int p = 0; p < 4; ++p)
        W1t[(size_t)(bn + ty + p * 8) * 512 + bk + tx] = (_Float16)tile[tx][ty + p * 8];
}

// ---------------- scan pass 1: per-block sums ----------------
__global__ __launch_bounds__(SCAN_BLK) void k_psum(const int* __restrict__ deg,
                                                   int* __restrict__ bsum, int N) {
    __shared__ int red[SCAN_BLK / 64];
    int i = blockIdx.x * SCAN_BLK + threadIdx.x;
    int v = (i < N) ? deg[i] : 0;
#pragma unroll
    for (int off = 32; off > 0; off >>= 1) v += __shfl_down(v, off);
    if ((threadIdx.x & 63) == 0) red[threadIdx.x >> 6] = v;
    __syncthreads();
    if (threadIdx.x == 0) {
        int s = 0;
#pragma unroll
        for (int u = 0; u < SCAN_BLK / 64; ++u) s += red[u];
        bsum[blockIdx.x] = s;
    }
}

// ---- scan pass 2: per-block scan + block-offset reduce (gridDim <= 64) ----
__global__ __launch_bounds__(SCAN_BLK) void k_write(const int* __restrict__ deg,
                                                    const int* __restrict__ bsum,
                                                    int* __restrict__ rp,
                                                    float* __restrict__ dis,
                                                    int* __restrict__ cursor, int N) {
    __shared__ int sums[SCAN_BLK];
    __shared__ int boff_s, tot_s;
    int t = threadIdx.x;
    if (t < 64) {
        int v = (t < (int)gridDim.x) ? bsum[t] : 0;
        int pre = (t < (int)blockIdx.x) ? v : 0;
        int a = pre, b = v;
#pragma unroll
        for (int off = 32; off > 0; off >>= 1) {
            a += __shfl_down(a, off);
            b += __shfl_down(b, off);
        }
        if (t == 0) { boff_s = a; tot_s = b; }
    }
    int i = blockIdx.x * SCAN_BLK + t;
    int d = (i < N) ? deg[i] : 0;
    sums[t] = d;
    __syncthreads();
    for (int off = 1; off < SCAN_BLK; off <<= 1) {
        int u = (t >= off) ? sums[t - off] : 0;
        __syncthreads();
        sums[t] += u;
        __syncthreads();
    }
    if (i < N) {
        rp[i] = boff_s + sums[t] - d;   // exclusive prefix
        dis[i] = rsqrtf((float)d + 1.0f);
        cursor[i] = 0;
    }
    if (blockIdx.x == gridDim.x - 1 && t == 0) rp[N] = tot_s;
}

// ------- merged2: blocks [0,nwg) = fused-cvt MFMA GEMM, [nwg,..) = CSR fill -------
// R11 x R12 combination: A fp32 loaded in regs, cvt to fp16, ds_write at SWIZZLED
// chunk (reg-staging can scatter; wave still writes 1KB contiguous -> conflict-free);
// B via global_load_lds with pre-swizzled source (R12, verified). Both sides use the
// involution: LDS chunk c of row r holds global chunk c^(r&7); ds_read XORs it back.
// No xh intermediate: saves 153 MB of HBM round-trip vs R12.
__global__ __launch_bounds__(256) void k_merged2(const float* __restrict__ A,
                                                 const _Float16* __restrict__ Bt,
                                                 _Float16* __restrict__ C,
                                                 int Nrows, int nbm, int nwg,
                                                 const int* __restrict__ ei,
                                                 const int* __restrict__ rp,
                                                 int* __restrict__ cursor,
                                                 int* __restrict__ csrc,
                                                 int E, int N) {
    __shared__ __align__(16) _Float16 As[128 * 64];
    __shared__ __align__(16) _Float16 Bs[128 * 64];

    if ((int)blockIdx.x >= nwg) {
        int e = ((int)blockIdx.x - nwg) * 256 + threadIdx.x;
        if (e < E) {
            int s = ei[e];
            int d = ei[E + e];
            if ((unsigned)s < (unsigned)N && (unsigned)d < (unsigned)N) {
                int pos = atomicAdd(&cursor[d], 1);
                csrc[rp[d] + pos] = s;
            }
        }
        return;
    }

    // ---- GEMM: y = cvt16(x) @ W1t^T (bn-fast + bijective XCD swizzle) ----
    const int g = (int)blockIdx.x;
    const int t = threadIdx.x;
    const int lane = t & 63, w = t >> 6;
    const int wm = w >> 1, wn = w & 1;

    const int q = nwg >> 3, r = nwg & 7;
    const int xcd = g & 7, within = g >> 3;
    const int wg = (xcd < r ? xcd * (q + 1) : r * (q + 1) + (xcd - r) * q) + within;
    const int bm = (wg >> 2) * 128, bn = (wg & 3) * 128;

    const int rr = lane & 15, kg = lane >> 4;
    const int lrow = lane >> 3;                            // B staging row-in-8
    const int scol = ((lane & 7) ^ lrow) * 8;              // B pre-swizzled source col
    const int rsw = rr & 7;                                // read-side row swizzle
    const int arow = t >> 3;                               // A staging row (0..31)
    const int achk = t & 7;                                // A LDS chunk
    const int agcol = (achk ^ (arow & 7)) * 8;             // A swizzled global col

    f32x4 acc[4][4];
#pragma unroll
    for (int i = 0; i < 4; ++i)
#pragma unroll
        for (int j = 0; j < 4; ++j) acc[i][j] = (f32x4)0.0f;

    for (int k0 = 0; k0 < 512; k0 += 64) {
        // B tile via async DMA (pre-swizzled source)
#pragma unroll
        for (int p = 0; p < 4; ++p) {
            const int row = p * 32 + w * 8 + lrow;
            gload_lds16(Bt + (size_t)(bn + row) * 512 + k0 + scol,
                        Bs + (p * 32 + w * 8) * 64);
        }
        // A tile: fp32 load -> cvt -> swizzled ds_write (wave writes 1KB contiguous)
#pragma unroll
        for (int p = 0; p < 4; ++p) {
            int grow = bm + p * 32 + arow;
            if (grow >= Nrows) grow = Nrows - 1;
            const float* gp = A + (size_t)grow * 512 + k0 + agcol;
            float4 u0 = *(const float4*)gp;
            float4 u1 = *(const float4*)(gp + 4);
            f16x8 o;
            o[0] = (_Float16)u0.x; o[1] = (_Float16)u0.y;
            o[2] = (_Float16)u0.z; o[3] = (_Float16)u0.w;
            o[4] = (_Float16)u1.x; o[5] = (_Float16)u1.y;
            o[6] = (_Float16)u1.z; o[7] = (_Float16)u1.w;
            *(f16x8*)(As + (p * 32 + arow) * 64 + achk * 8) = o;
        }
        __syncthreads();
#pragma unroll
        for (int kk = 0; kk < 2; ++kk) {
            f16x8 a[4], b[4];
#pragma unroll
            for (int i = 0; i < 4; ++i)
                a[i] = *(const f16x8*)(As + (wm * 64 + i * 16 + rr) * 64 +
                                       (((kk << 2) + kg) ^ rsw) * 8);
#pragma unroll
            for (int j = 0; j < 4; ++j)
                b[j] = *(const f16x8*)(Bs + (wn * 64 + j * 16 + rr) * 64 +
                                       (((kk << 2) + kg) ^ rsw) * 8);
#pragma unroll
            for (int i = 0; i < 4; ++i)
#pragma unroll
                for (int j = 0; j < 4; ++j)
                    acc[i][j] = __builtin_amdgcn_mfma_f32_16x16x32_f16(a[i], b[j], acc[i][j], 0, 0, 0);
        }
        __syncthreads();
    }

    // C/D layout: col = lane&15, row = (lane>>4)*4 + reg
#pragma unroll
    for (int i = 0; i < 4; ++i)
#pragma unroll
        for (int j = 0; j < 4; ++j)
#pragma unroll
            for (int reg = 0; reg < 4; ++reg) {
                int m = bm + wm * 64 + i * 16 + kg * 4 + reg;
                int n = bn + wn * 64 + j * 16 + rr;
                C[(size_t)m * 512 + n] = (_Float16)acc[i][j][reg];
            }
}

// ---------------- layer-1 aggregation (R8 form: full width, unroll 8) ----------------
// R9/R10 lesson: channel-slicing cuts FETCH but time tracks slice count; R8's
// ~3.6 TB/s on the cross-L2 gather path is the practical floor. Do not touch.
__global__ __launch_bounds__(256) void k_agg(const _Float16* __restrict__ y,
                                             const float* __restrict__ dis,
                                             const int* __restrict__ rp,
                                             const int* __restrict__ csrc,
                                             const float* __restrict__ b1,
                                             const float* __restrict__ W2,
                                             float* __restrict__ z, int N) {
    const int n = blockIdx.x * 4 + (threadIdx.x >> 6);
    if (n >= N) return;
    const int l = threadIdx.x & 63;

    const float d1 = dis[n];
    f16x8 self = *(const f16x8*)(y + (size_t)n * 512 + l * 8);
    float acc[8];
#pragma unroll
    for (int c = 0; c < 8; ++c) acc[c] = d1 * (float)self[c];

    int j = rp[n], jend = rp[n + 1];
    for (; j + 8 <= jend; j += 8) {
        int s[8]; float wt[8]; f16x8 v[8];
#pragma unroll
        for (int u = 0; u < 8; ++u) s[u] = csrc[j + u];
#pragma unroll
        for (int u = 0; u < 8; ++u) wt[u] = dis[s[u]];
#pragma unroll
        for (int u = 0; u < 8; ++u)
            v[u] = *(const f16x8*)(y + (size_t)s[u] * 512 + l * 8);
#pragma unroll
        for (int u = 0; u < 8; ++u)
#pragma unroll
            for (int c = 0; c < 8; ++c) acc[c] += wt[u] * (float)v[u][c];
    }
    for (; j + 2 <= jend; j += 2) {
        int s0 = csrc[j], s1 = csrc[j + 1];
        float w0 = dis[s0], w1 = dis[s1];
        f16x8 v0 = *(const f16x8*)(y + (size_t)s0 * 512 + l * 8);
        f16x8 v1 = *(const f16x8*)(y + (size_t)s1 * 512 + l * 8);
#pragma unroll
        for (int c = 0; c < 8; ++c) acc[c] += w0 * (float)v0[c] + w1 * (float)v1[c];
    }
    if (j < jend) {
        int s0 = csrc[j];
        float w0 = dis[s0];
        f16x8 v0 = *(const f16x8*)(y + (size_t)s0 * 512 + l * 8);
#pragma unroll
        for (int c = 0; c < 8; ++c) acc[c] += w0 * (float)v0[c];
    }

    float4 bb0 = *(const float4*)(b1 + l * 8);
    float4 bb1 = *(const float4*)(b1 + l * 8 + 4);
    float4 w20 = *(const float4*)(W2 + l * 8);
    float4 w21 = *(const float4*)(W2 + l * 8 + 4);
    float bbv[8] = {bb0.x, bb0.y, bb0.z, bb0.w, bb1.x, bb1.y, bb1.z, bb1.w};
    float w2v[8] = {w20.x, w20.y, w20.z, w20.w, w21.x, w21.y, w21.z, w21.w};
    float p = 0.0f;
#pragma unroll
    for (int c = 0; c < 8; ++c) {
        float h = fmaxf(acc[c] * d1 + bbv[c], 0.0f);
        p += h * w2v[c];
    }
#pragma unroll
    for (int off = 32; off > 0; off >>= 1) p += __shfl_down(p, off);
    if (l == 0) z[n] = d1 * p;
}

// ---------------- layer-2 aggregation on prescaled scalars ----------------
__global__ void k_out(const float* __restrict__ z, const float* __restrict__ dis,
                      const int* __restrict__ rp, const int* __restrict__ csrc,
                      const float* __restrict__ b2, float* __restrict__ out, int N) {
    int n = blockIdx.x * blockDim.x + threadIdx.x;
    if (n >= N) return;
    float acc = z[n];
    int j = rp[n], jend = rp[n + 1];
    for (; j + 4 <= jend; j += 4) {
        float a0 = z[csrc[j]];
        float a1 = z[csrc[j + 1]];
        float a2 = z[csrc[j + 2]];
        float a3 = z[csrc[j + 3]];
        acc += (a0 + a1) + (a2 + a3);
    }
    for (; j < jend; ++j) acc += z[csrc[j]];
    out[n] = dis[n] * acc + b2[0];
}

extern "C" void kernel_launch(void* const* d_in, const int* in_sizes, int n_in,
                              void* d_out, int out_size, void* d_ws, size_t ws_size,
                              hipStream_t stream) {
    const float* x  = (const float*)d_in[0];
    const int*   ei = (const int*)d_in[1];
    const float* W1 = (const float*)d_in[2];
    const float* b1 = (const float*)d_in[3];
    const float* W2 = (const float*)d_in[4];
    const float* b2 = (const float*)d_in[5];
    float* out = (float*)d_out;

    const int N = in_sizes[0] / IN_CH;            // 50000
    const int E = in_sizes[1] / 2;                // 800000
    const int nbm = (N + 127) / 128;              // 391
    const int M2 = nbm * 128;                     // 50048
    const int NB = (N + SCAN_BLK - 1) / SCAN_BLK; // 49 (<= 64 for k_write)
    const int DEGB = (E + 255) / 256;             // 3125
    const int nwg  = nbm * 4;                     // 1564

    char* ws = (char*)d_ws;
    size_t off = 0;
    auto alloc = [&](size_t bytes) {
        char* p = ws + off;
        off += (bytes + 255) & ~(size_t)255;
        return p;
    };
    _Float16* y   = (_Float16*)alloc((size_t)M2 * 512 * sizeof(_Float16)); // 51.25 MB
    _Float16* W1t = (_Float16*)alloc((size_t)512 * 512 * sizeof(_Float16));
    int*   deg    = (int*)alloc((size_t)N * sizeof(int));
    float* dis    = (float*)alloc((size_t)N * sizeof(float));
    int*   rp     = (int*)alloc((size_t)(N + 1) * sizeof(int));
    int*   cursor = (int*)alloc((size_t)N * sizeof(int));
    int*   csrc   = (int*)alloc((size_t)E * sizeof(int));
    float* z      = (float*)alloc((size_t)N * sizeof(float));
    int*   bsum   = (int*)alloc((size_t)64 * sizeof(int));

    hipMemsetAsync(deg, 0, (size_t)N * sizeof(int), stream);

    k_merged1<<<256 + DEGB, 256, 0, stream>>>(W1, W1t, ei + E, deg, E, N);
    k_psum<<<NB, SCAN_BLK, 0, stream>>>(deg, bsum, N);
    k_write<<<NB, SCAN_BLK, 0, stream>>>(deg, bsum, rp, dis, cursor, N);
    k_merged2<<<nwg + DEGB, 256, 0, stream>>>(x, W1t, y, N, nbm, nwg,
                                              ei, rp, cursor, csrc, E, N);
    k_agg<<<(N + 3) / 4, 256, 0, stream>>>(y, dis, rp, csrc, b1, W2, z, N);
    k_out<<<(N + 255) / 256, 256, 0, stream>>>(z, dis, rp, csrc, b2, out, N);
}

// Round 14
// 246.656 us; speedup vs baseline: 1.1008x; 1.0175x over previous
//
#include <hip/hip_runtime.h>

#define IN_CH 512
#define SCAN_BLK 1024

typedef _Float16 f16x8 __attribute__((ext_vector_type(8)));
typedef float f32x4 __attribute__((ext_vector_type(4)));

// async global->LDS, 16B per lane. LDS dest is wave-uniform base + lane*16.
__device__ __forceinline__ void gload_lds16(const void* g, void* l) {
    __builtin_amdgcn_global_load_lds(
        (const __attribute__((address_space(1))) unsigned int*)g,
        (__attribute__((address_space(3))) unsigned int*)l, 16, 0, 0);
}

// ------- merged1: blocks [0,256) = W1 cvt+transpose, rest = degree count -------
__global__ __launch_bounds__(256) void k_merged1(const float* __restrict__ W1,
                                                 _Float16* __restrict__ W1t,
                                                 const int* __restrict__ col,
                                                 int* __restrict__ deg, int E, int N) {
    __shared__ float tile[32][33];
    if ((int)blockIdx.x >= 256) {
        int e = ((int)blockIdx.x - 256) * 256 + threadIdx.x;
        if (e < E) {
            int d = col[e];
            if ((unsigned)d < (unsigned)N) atomicAdd(&deg[d], 1);
        }
        return;
    }
    const int bk = (blockIdx.x & 15) * 32, bn = (blockIdx.x >> 4) * 32;
    const int tx = threadIdx.x & 31, ty = threadIdx.x >> 5;   // 32 x 8
#pragma unroll
    for (int p = 0; p < 4; ++p)
        tile[ty + p * 8][tx] = W1[(size_t)(bk + ty + p * 8) * 512 + bn + tx];
    __syncthreads();
#pragma unroll
    for (int p = 0; p < 4; ++p)
        W1t[(size_t)(bn + ty + p * 8) * 512 + bk + tx] = (_Float16)tile[tx][ty + p * 8];
}

// ---------------- scan pass 1: per-block sums ----------------
__global__ __launch_bounds__(SCAN_BLK) void k_psum(const int* __restrict__ deg,
                                                   int* __restrict__ bsum, int N) {
    __shared__ int red[SCAN_BLK / 64];
    int i = blockIdx.x * SCAN_BLK + threadIdx.x;
    int v = (i < N) ? deg[i] : 0;
#pragma unroll
    for (int off = 32; off > 0; off >>= 1) v += __shfl_down(v, off);
    if ((threadIdx.x & 63) == 0) red[threadIdx.x >> 6] = v;
    __syncthreads();
    if (threadIdx.x == 0) {
        int s = 0;
#pragma unroll
        for (int u = 0; u < SCAN_BLK / 64; ++u) s += red[u];
        bsum[blockIdx.x] = s;
    }
}

// ---- scan pass 2: per-block scan + block-offset reduce (gridDim <= 64) ----
__global__ __launch_bounds__(SCAN_BLK) void k_write(const int* __restrict__ deg,
                                                    const int* __restrict__ bsum,
                                                    int* __restrict__ rp,
                                                    float* __restrict__ dis,
                                                    int* __restrict__ cursor, int N) {
    __shared__ int sums[SCAN_BLK];
    __shared__ int boff_s, tot_s;
    int t = threadIdx.x;
    if (t < 64) {
        int v = (t < (int)gridDim.x) ? bsum[t] : 0;
        int pre = (t < (int)blockIdx.x) ? v : 0;
        int a = pre, b = v;
#pragma unroll
        for (int off = 32; off > 0; off >>= 1) {
            a += __shfl_down(a, off);
            b += __shfl_down(b, off);
        }
        if (t == 0) { boff_s = a; tot_s = b; }
    }
    int i = blockIdx.x * SCAN_BLK + t;
    int d = (i < N) ? deg[i] : 0;
    sums[t] = d;
    __syncthreads();
    for (int off = 1; off < SCAN_BLK; off <<= 1) {
        int u = (t >= off) ? sums[t - off] : 0;
        __syncthreads();
        sums[t] += u;
        __syncthreads();
    }
    if (i < N) {
        rp[i] = boff_s + sums[t] - d;   // exclusive prefix
        dis[i] = rsqrtf((float)d + 1.0f);
        cursor[i] = 0;
    }
    if (blockIdx.x == gridDim.x - 1 && t == 0) rp[N] = tot_s;
}

// ------- merged2: blocks [0,nwg) = fused-cvt MFMA GEMM, [nwg,..) = CSR fill -------
// R13 + T14 async-STAGE on A: next K-step's A tile loaded into regs right after
// barrier #1, so the HBM/L2 latency hides under the 32-MFMA section instead of
// serializing after barrier #2. Both LDS operands conflict-free via the XOR
// involution (chunk c of row r holds global chunk c^(r&7)). Epilogue prescales
// y rows by dis[m] (R7 form: removes the per-edge dis gather from k_agg).
__global__ __launch_bounds__(256) void k_merged2(const float* __restrict__ A,
                                                 const _Float16* __restrict__ Bt,
                                                 const float* __restrict__ dis,
                                                 _Float16* __restrict__ C,
                                                 int Nrows, int nbm, int nwg,
                                                 const int* __restrict__ ei,
                                                 const int* __restrict__ rp,
                                                 int* __restrict__ cursor,
                                                 int* __restrict__ csrc,
                                                 int E, int N) {
    __shared__ __align__(16) _Float16 As[128 * 64];
    __shared__ __align__(16) _Float16 Bs[128 * 64];

    if ((int)blockIdx.x >= nwg) {
        int e = ((int)blockIdx.x - nwg) * 256 + threadIdx.x;
        if (e < E) {
            int s = ei[e];
            int d = ei[E + e];
            if ((unsigned)s < (unsigned)N && (unsigned)d < (unsigned)N) {
                int pos = atomicAdd(&cursor[d], 1);
                csrc[rp[d] + pos] = s;
            }
        }
        return;
    }

    // ---- GEMM: y = dis * (cvt16(x) @ W1t^T)  (bn-fast + bijective XCD swizzle) ----
    const int g = (int)blockIdx.x;
    const int t = threadIdx.x;
    const int lane = t & 63, w = t >> 6;
    const int wm = w >> 1, wn = w & 1;

    const int q = nwg >> 3, r = nwg & 7;
    const int xcd = g & 7, within = g >> 3;
    const int wg = (xcd < r ? xcd * (q + 1) : r * (q + 1) + (xcd - r) * q) + within;
    const int bm = (wg >> 2) * 128, bn = (wg & 3) * 128;

    const int rr = lane & 15, kg = lane >> 4;
    const int lrow = lane >> 3;                            // B staging row-in-8
    const int scol = ((lane & 7) ^ lrow) * 8;              // B pre-swizzled source col
    const int rsw = rr & 7;                                // read-side row swizzle
    const int arow = t >> 3;                               // A staging row (0..31)
    const int achk = t & 7;                                // A LDS chunk
    const int agcol = (achk ^ (arow & 7)) * 8;             // A swizzled global col

    // T14: per-row base pointers + register-held A tile (prefetched)
    const float* Abase[4];
#pragma unroll
    for (int p = 0; p < 4; ++p) {
        int grow = bm + p * 32 + arow;
        if (grow >= Nrows) grow = Nrows - 1;
        Abase[p] = A + (size_t)grow * 512 + agcol;
    }
    float4 pa[4], pb[4];
#pragma unroll
    for (int p = 0; p < 4; ++p) {
        pa[p] = *(const float4*)(Abase[p]);
        pb[p] = *(const float4*)(Abase[p] + 4);
    }

    f32x4 acc[4][4];
#pragma unroll
    for (int i = 0; i < 4; ++i)
#pragma unroll
        for (int j = 0; j < 4; ++j) acc[i][j] = (f32x4)0.0f;

    for (int k0 = 0; k0 < 512; k0 += 64) {
        // B tile via async DMA (pre-swizzled source)
#pragma unroll
        for (int p = 0; p < 4; ++p) {
            const int row = p * 32 + w * 8 + lrow;
            gload_lds16(Bt + (size_t)(bn + row) * 512 + k0 + scol,
                        Bs + (p * 32 + w * 8) * 64);
        }
        // A tile: cvt prefetched regs -> swizzled ds_write
#pragma unroll
        for (int p = 0; p < 4; ++p) {
            f16x8 o;
            o[0] = (_Float16)pa[p].x; o[1] = (_Float16)pa[p].y;
            o[2] = (_Float16)pa[p].z; o[3] = (_Float16)pa[p].w;
            o[4] = (_Float16)pb[p].x; o[5] = (_Float16)pb[p].y;
            o[6] = (_Float16)pb[p].z; o[7] = (_Float16)pb[p].w;
            *(f16x8*)(As + (p * 32 + arow) * 64 + achk * 8) = o;
        }
        __syncthreads();
        // issue next A loads NOW -> latency hides under the MFMA section
        if (k0 + 64 < 512) {
#pragma unroll
            for (int p = 0; p < 4; ++p) {
                pa[p] = *(const float4*)(Abase[p] + k0 + 64);
                pb[p] = *(const float4*)(Abase[p] + k0 + 68);
            }
        }
#pragma unroll
        for (int kk = 0; kk < 2; ++kk) {
            f16x8 a[4], b[4];
#pragma unroll
            for (int i = 0; i < 4; ++i)
                a[i] = *(const f16x8*)(As + (wm * 64 + i * 16 + rr) * 64 +
                                       (((kk << 2) + kg) ^ rsw) * 8);
#pragma unroll
            for (int j = 0; j < 4; ++j)
                b[j] = *(const f16x8*)(Bs + (wn * 64 + j * 16 + rr) * 64 +
                                       (((kk << 2) + kg) ^ rsw) * 8);
#pragma unroll
            for (int i = 0; i < 4; ++i)
#pragma unroll
                for (int j = 0; j < 4; ++j)
                    acc[i][j] = __builtin_amdgcn_mfma_f32_16x16x32_f16(a[i], b[j], acc[i][j], 0, 0, 0);
        }
        __syncthreads();
    }

    // C/D layout: col = lane&15, row = (lane>>4)*4 + reg. Prescale row by dis[m].
#pragma unroll
    for (int i = 0; i < 4; ++i)
#pragma unroll
        for (int reg = 0; reg < 4; ++reg) {
            int m = bm + wm * 64 + i * 16 + kg * 4 + reg;
            int mc = (m < Nrows) ? m : Nrows - 1;
            float dm = dis[mc];
#pragma unroll
            for (int j = 0; j < 4; ++j) {
                int n = bn + wn * 64 + j * 16 + rr;
                C[(size_t)m * 512 + n] = (_Float16)(acc[i][j][reg] * dm);
            }
        }
}

// ---------------- layer-1 aggregation (R7 form: y prescaled by dis) ----------------
// agg_inner = y[n] + sum y[src] (all prescaled); h = relu(d1*inner + b1); z = d1*(h.W2)
// R9/R10 lesson: channel-slicing is a dead end; ~3.65 TB/s gather is the floor.
__global__ __launch_bounds__(256) void k_agg(const _Float16* __restrict__ y,
                                             const float* __restrict__ dis,
                                             const int* __restrict__ rp,
                                             const int* __restrict__ csrc,
                                             const float* __restrict__ b1,
                                             const float* __restrict__ W2,
                                             float* __restrict__ z, int N) {
    const int n = blockIdx.x * 4 + (threadIdx.x >> 6);
    if (n >= N) return;
    const int l = threadIdx.x & 63;

    const float d1 = dis[n];
    f16x8 self = *(const f16x8*)(y + (size_t)n * 512 + l * 8);
    float acc[8];
#pragma unroll
    for (int c = 0; c < 8; ++c) acc[c] = (float)self[c];

    int j = rp[n], jend = rp[n + 1];
    for (; j + 8 <= jend; j += 8) {
        int s[8]; f16x8 v[8];
#pragma unroll
        for (int u = 0; u < 8; ++u) s[u] = csrc[j + u];
#pragma unroll
        for (int u = 0; u < 8; ++u)
            v[u] = *(const f16x8*)(y + (size_t)s[u] * 512 + l * 8);
#pragma unroll
        for (int u = 0; u < 8; ++u)
#pragma unroll
            for (int c = 0; c < 8; ++c) acc[c] += (float)v[u][c];
    }
    for (; j + 2 <= jend; j += 2) {
        int s0 = csrc[j], s1 = csrc[j + 1];
        f16x8 v0 = *(const f16x8*)(y + (size_t)s0 * 512 + l * 8);
        f16x8 v1 = *(const f16x8*)(y + (size_t)s1 * 512 + l * 8);
#pragma unroll
        for (int c = 0; c < 8; ++c) acc[c] += (float)v0[c] + (float)v1[c];
    }
    if (j < jend) {
        f16x8 v0 = *(const f16x8*)(y + (size_t)csrc[j] * 512 + l * 8);
#pragma unroll
        for (int c = 0; c < 8; ++c) acc[c] += (float)v0[c];
    }

    float4 bb0 = *(const float4*)(b1 + l * 8);
    float4 bb1 = *(const float4*)(b1 + l * 8 + 4);
    float4 w20 = *(const float4*)(W2 + l * 8);
    float4 w21 = *(const float4*)(W2 + l * 8 + 4);
    float bbv[8] = {bb0.x, bb0.y, bb0.z, bb0.w, bb1.x, bb1.y, bb1.z, bb1.w};
    float w2v[8] = {w20.x, w20.y, w20.z, w20.w, w21.x, w21.y, w21.z, w21.w};
    float p = 0.0f;
#pragma unroll
    for (int c = 0; c < 8; ++c) {
        float h = fmaxf(acc[c] * d1 + bbv[c], 0.0f);
        p += h * w2v[c];
    }
#pragma unroll
    for (int off = 32; off > 0; off >>= 1) p += __shfl_down(p, off);
    if (l == 0) z[n] = d1 * p;
}

// ---------------- layer-2 aggregation on prescaled scalars ----------------
__global__ void k_out(const float* __restrict__ z, const float* __restrict__ dis,
                      const int* __restrict__ rp, const int* __restrict__ csrc,
                      const float* __restrict__ b2, float* __restrict__ out, int N) {
    int n = blockIdx.x * blockDim.x + threadIdx.x;
    if (n >= N) return;
    float acc = z[n];
    int j = rp[n], jend = rp[n + 1];
    for (; j + 4 <= jend; j += 4) {
        float a0 = z[csrc[j]];
        float a1 = z[csrc[j + 1]];
        float a2 = z[csrc[j + 2]];
        float a3 = z[csrc[j + 3]];
        acc += (a0 + a1) + (a2 + a3);
    }
    for (; j < jend; ++j) acc += z[csrc[j]];
    out[n] = dis[n] * acc + b2[0];
}

extern "C" void kernel_launch(void* const* d_in, const int* in_sizes, int n_in,
                              void* d_out, int out_size, void* d_ws, size_t ws_size,
                              hipStream_t stream) {
    const float* x  = (const float*)d_in[0];
    const int*   ei = (const int*)d_in[1];
    const float* W1 = (const float*)d_in[2];
    const float* b1 = (const float*)d_in[3];
    const float* W2 = (const float*)d_in[4];
    const float* b2 = (const float*)d_in[5];
    float* out = (float*)d_out;

    const int N = in_sizes[0] / IN_CH;            // 50000
    const int E = in_sizes[1] / 2;                // 800000
    const int nbm = (N + 127) / 128;              // 391
    const int M2 = nbm * 128;                     // 50048
    const int NB = (N + SCAN_BLK - 1) / SCAN_BLK; // 49 (<= 64 for k_write)
    const int DEGB = (E + 255) / 256;             // 3125
    const int nwg  = nbm * 4;                     // 1564

    char* ws = (char*)d_ws;
    size_t off = 0;
    auto alloc = [&](size_t bytes) {
        char* p = ws + off;
        off += (bytes + 255) & ~(size_t)255;
        return p;
    };
    _Float16* y   = (_Float16*)alloc((size_t)M2 * 512 * sizeof(_Float16)); // 51.25 MB
    _Float16* W1t = (_Float16*)alloc((size_t)512 * 512 * sizeof(_Float16));
    int*   deg    = (int*)alloc((size_t)N * sizeof(int));
    float* dis    = (float*)alloc((size_t)N * sizeof(float));
    int*   rp     = (int*)alloc((size_t)(N + 1) * sizeof(int));
    int*   cursor = (int*)alloc((size_t)N * sizeof(int));
    int*   csrc   = (int*)alloc((size_t)E * sizeof(int));
    float* z      = (float*)alloc((size_t)N * sizeof(float));
    int*   bsum   = (int*)alloc((size_t)64 * sizeof(int));

    hipMemsetAsync(deg, 0, (size_t)N * sizeof(int), stream);

    k_merged1<<<256 + DEGB, 256, 0, stream>>>(W1, W1t, ei + E, deg, E, N);
    k_psum<<<NB, SCAN_BLK, 0, stream>>>(deg, bsum, N);
    k_write<<<NB, SCAN_BLK, 0, stream>>>(deg, bsum, rp, dis, cursor, N);
    k_merged2<<<nwg + DEGB, 256, 0, stream>>>(x, W1t, dis, y, N, nbm, nwg,
                                              ei, rp, cursor, csrc, E, N);
    k_agg<<<(N + 3) / 4, 256, 0, stream>>>(y, dis, rp, csrc, b1, W2, z, N);
    k_out<<<(N + 255) / 256, 256, 0, stream>>>(z, dis, rp, csrc, b2, out, N);
}

// Round 15
// 237.983 us; speedup vs baseline: 1.1410x; 1.0364x over previous
//
#include <hip/hip_runtime.h>

#define IN_CH 512
#define SCAN_BLK 1024

typedef _Float16 f16x8 __attribute__((ext_vector_type(8)));
typedef float f32x4 __attribute__((ext_vector_type(4)));

// async global->LDS, 16B per lane. LDS dest is wave-uniform base + lane*16.
__device__ __forceinline__ void gload_lds16(const void* g, void* l) {
    __builtin_amdgcn_global_load_lds(
        (const __attribute__((address_space(1))) unsigned int*)g,
        (__attribute__((address_space(3))) unsigned int*)l, 16, 0, 0);
}

// ------- merged1: blocks [0,256) = W1 cvt+transpose, rest = degree count -------
__global__ __launch_bounds__(256) void k_merged1(const float* __restrict__ W1,
                                                 _Float16* __restrict__ W1t,
                                                 const int* __restrict__ col,
                                                 int* __restrict__ deg, int E, int N) {
    __shared__ float tile[32][33];
    if ((int)blockIdx.x >= 256) {
        int e = ((int)blockIdx.x - 256) * 256 + threadIdx.x;
        if (e < E) {
            int d = col[e];
            if ((unsigned)d < (unsigned)N) atomicAdd(&deg[d], 1);
        }
        return;
    }
    const int bk = (blockIdx.x & 15) * 32, bn = (blockIdx.x >> 4) * 32;
    const int tx = threadIdx.x & 31, ty = threadIdx.x >> 5;   // 32 x 8
#pragma unroll
    for (int p = 0; p < 4; ++p)
        tile[ty + p * 8][tx] = W1[(size_t)(bk + ty + p * 8) * 512 + bn + tx];
    __syncthreads();
#pragma unroll
    for (int p = 0; p < 4; ++p)
        W1t[(size_t)(bn + ty + p * 8) * 512 + bk + tx] = (_Float16)tile[tx][ty + p * 8];
}

// ---------------- scan pass 1: per-block sums ----------------
__global__ __launch_bounds__(SCAN_BLK) void k_psum(const int* __restrict__ deg,
                                                   int* __restrict__ bsum, int N) {
    __shared__ int red[SCAN_BLK / 64];
    int i = blockIdx.x * SCAN_BLK + threadIdx.x;
    int v = (i < N) ? deg[i] : 0;
#pragma unroll
    for (int off = 32; off > 0; off >>= 1) v += __shfl_down(v, off);
    if ((threadIdx.x & 63) == 0) red[threadIdx.x >> 6] = v;
    __syncthreads();
    if (threadIdx.x == 0) {
        int s = 0;
#pragma unroll
        for (int u = 0; u < SCAN_BLK / 64; ++u) s += red[u];
        bsum[blockIdx.x] = s;
    }
}

// ---- scan pass 2: per-block scan + block-offset reduce (gridDim <= 64) ----
__global__ __launch_bounds__(SCAN_BLK) void k_write(const int* __restrict__ deg,
                                                    const int* __restrict__ bsum,
                                                    int* __restrict__ rp,
                                                    float* __restrict__ dis,
                                                    int* __restrict__ cursor, int N) {
    __shared__ int sums[SCAN_BLK];
    __shared__ int boff_s, tot_s;
    int t = threadIdx.x;
    if (t < 64) {
        int v = (t < (int)gridDim.x) ? bsum[t] : 0;
        int pre = (t < (int)blockIdx.x) ? v : 0;
        int a = pre, b = v;
#pragma unroll
        for (int off = 32; off > 0; off >>= 1) {
            a += __shfl_down(a, off);
            b += __shfl_down(b, off);
        }
        if (t == 0) { boff_s = a; tot_s = b; }
    }
    int i = blockIdx.x * SCAN_BLK + t;
    int d = (i < N) ? deg[i] : 0;
    sums[t] = d;
    __syncthreads();
    for (int off = 1; off < SCAN_BLK; off <<= 1) {
        int u = (t >= off) ? sums[t - off] : 0;
        __syncthreads();
        sums[t] += u;
        __syncthreads();
    }
    if (i < N) {
        rp[i] = boff_s + sums[t] - d;   // exclusive prefix
        dis[i] = rsqrtf((float)d + 1.0f);
        cursor[i] = 0;
    }
    if (blockIdx.x == gridDim.x - 1 && t == 0) rp[N] = tot_s;
}

// ------- merged2: blocks [0,nwg) = 128x256 fused-cvt MFMA GEMM, rest = CSR fill -------
// R15: BN=256 (A cvt-redundancy 4x->2x, barrier-drains per output halved), 512 thr,
// 8 waves 2x4 (wave tile 64x64, acc 4x4). __launch_bounds__(512,4) targets <=128 VGPR
// so 2 blocks/CU (16 waves) — preserves latency-hiding (m132 occupancy lesson).
// Both LDS operands conflict-free via the XOR involution (verified R12-R14).
__global__ __launch_bounds__(512, 4) void k_merged2(const float* __restrict__ A,
                                                    const _Float16* __restrict__ Bt,
                                                    const float* __restrict__ dis,
                                                    _Float16* __restrict__ C,
                                                    int Nrows, int nbm, int nwg,
                                                    const int* __restrict__ ei,
                                                    const int* __restrict__ rp,
                                                    int* __restrict__ cursor,
                                                    int* __restrict__ csrc,
                                                    int E, int N) {
    __shared__ __align__(16) _Float16 As[128 * 64];   // 16 KB
    __shared__ __align__(16) _Float16 Bs[256 * 64];   // 32 KB

    if ((int)blockIdx.x >= nwg) {
        int e = ((int)blockIdx.x - nwg) * 512 + threadIdx.x;
        if (e < E) {
            int s = ei[e];
            int d = ei[E + e];
            if ((unsigned)s < (unsigned)N && (unsigned)d < (unsigned)N) {
                int pos = atomicAdd(&cursor[d], 1);
                csrc[rp[d] + pos] = s;
            }
        }
        return;
    }

    // ---- GEMM: y = dis * (cvt16(x) @ W1t^T), tile 128x256 ----
    const int g = (int)blockIdx.x;
    const int t = threadIdx.x;
    const int lane = t & 63, w = t >> 6;           // 8 waves
    const int wm = w >> 2, wn = w & 3;             // 2x4 wave grid

    const int q = nwg >> 3, r = nwg & 7;
    const int xcd = g & 7, within = g >> 3;
    const int wg = (xcd < r ? xcd * (q + 1) : r * (q + 1) + (xcd - r) * q) + within;
    const int bm = (wg >> 1) * 128, bn = (wg & 1) * 256;

    const int rr = lane & 15, kg = lane >> 4;
    const int lrow = lane >> 3;                    // B staging row-in-8
    const int scol = ((lane & 7) ^ lrow) * 8;      // B pre-swizzled source col
    const int rsw = rr & 7;                        // read-side row swizzle
    const int arow = t >> 3;                       // A staging row (0..63)
    const int achk = t & 7;                        // A LDS chunk
    const int agcol = (achk ^ (arow & 7)) * 8;     // A swizzled global col

    const float* Abase[2];
#pragma unroll
    for (int p = 0; p < 2; ++p) {
        int grow = bm + p * 64 + arow;
        if (grow >= Nrows) grow = Nrows - 1;
        Abase[p] = A + (size_t)grow * 512 + agcol;
    }

    f32x4 acc[4][4];
#pragma unroll
    for (int i = 0; i < 4; ++i)
#pragma unroll
        for (int j = 0; j < 4; ++j) acc[i][j] = (f32x4)0.0f;

    for (int k0 = 0; k0 < 512; k0 += 64) {
        // B tile (256x64) via async DMA, pre-swizzled source: 4 issues/wave
#pragma unroll
        for (int p = 0; p < 4; ++p) {
            const int row = p * 64 + w * 8 + lrow;
            gload_lds16(Bt + (size_t)(bn + row) * 512 + k0 + scol,
                        Bs + (p * 64 + w * 8) * 64);
        }
        // A tile (128x64): fp32 load -> cvt -> swizzled ds_write (2 rows/thread)
#pragma unroll
        for (int p = 0; p < 2; ++p) {
            const float* gp = Abase[p] + k0;
            float4 u0 = *(const float4*)gp;
            float4 u1 = *(const float4*)(gp + 4);
            f16x8 o;
            o[0] = (_Float16)u0.x; o[1] = (_Float16)u0.y;
            o[2] = (_Float16)u0.z; o[3] = (_Float16)u0.w;
            o[4] = (_Float16)u1.x; o[5] = (_Float16)u1.y;
            o[6] = (_Float16)u1.z; o[7] = (_Float16)u1.w;
            *(f16x8*)(As + (p * 64 + arow) * 64 + achk * 8) = o;
        }
        __syncthreads();
#pragma unroll
        for (int kk = 0; kk < 2; ++kk) {
            f16x8 a[4], b[4];
#pragma unroll
            for (int i = 0; i < 4; ++i)
                a[i] = *(const f16x8*)(As + (wm * 64 + i * 16 + rr) * 64 +
                                       (((kk << 2) + kg) ^ rsw) * 8);
#pragma unroll
            for (int j = 0; j < 4; ++j)
                b[j] = *(const f16x8*)(Bs + (wn * 64 + j * 16 + rr) * 64 +
                                       (((kk << 2) + kg) ^ rsw) * 8);
#pragma unroll
            for (int i = 0; i < 4; ++i)
#pragma unroll
                for (int j = 0; j < 4; ++j)
                    acc[i][j] = __builtin_amdgcn_mfma_f32_16x16x32_f16(a[i], b[j], acc[i][j], 0, 0, 0);
        }
        __syncthreads();
    }

    // C/D layout: col = lane&15, row = (lane>>4)*4 + reg. Prescale row by dis[m].
#pragma unroll
    for (int i = 0; i < 4; ++i)
#pragma unroll
        for (int reg = 0; reg < 4; ++reg) {
            int m = bm + wm * 64 + i * 16 + kg * 4 + reg;
            int mc = (m < Nrows) ? m : Nrows - 1;
            float dm = dis[mc];
#pragma unroll
            for (int j = 0; j < 4; ++j) {
                int n = bn + wn * 64 + j * 16 + rr;
                C[(size_t)m * 512 + n] = (_Float16)(acc[i][j][reg] * dm);
            }
        }
}

// ---------------- layer-1 aggregation (R7/R14 form: y prescaled by dis) ----------------
// ~3.65 TB/s cross-L2 gather floor (R8-R14 stable). Do not touch.
__global__ __launch_bounds__(256) void k_agg(const _Float16* __restrict__ y,
                                             const float* __restrict__ dis,
                                             const int* __restrict__ rp,
                                             const int* __restrict__ csrc,
                                             const float* __restrict__ b1,
                                             const float* __restrict__ W2,
                                             float* __restrict__ z, int N) {
    const int n = blockIdx.x * 4 + (threadIdx.x >> 6);
    if (n >= N) return;
    const int l = threadIdx.x & 63;

    const float d1 = dis[n];
    f16x8 self = *(const f16x8*)(y + (size_t)n * 512 + l * 8);
    float acc[8];
#pragma unroll
    for (int c = 0; c < 8; ++c) acc[c] = (float)self[c];

    int j = rp[n], jend = rp[n + 1];
    for (; j + 8 <= jend; j += 8) {
        int s[8]; f16x8 v[8];
#pragma unroll
        for (int u = 0; u < 8; ++u) s[u] = csrc[j + u];
#pragma unroll
        for (int u = 0; u < 8; ++u)
            v[u] = *(const f16x8*)(y + (size_t)s[u] * 512 + l * 8);
#pragma unroll
        for (int u = 0; u < 8; ++u)
#pragma unroll
            for (int c = 0; c < 8; ++c) acc[c] += (float)v[u][c];
    }
    for (; j + 2 <= jend; j += 2) {
        int s0 = csrc[j], s1 = csrc[j + 1];
        f16x8 v0 = *(const f16x8*)(y + (size_t)s0 * 512 + l * 8);
        f16x8 v1 = *(const f16x8*)(y + (size_t)s1 * 512 + l * 8);
#pragma unroll
        for (int c = 0; c < 8; ++c) acc[c] += (float)v0[c] + (float)v1[c];
    }
    if (j < jend) {
        f16x8 v0 = *(const f16x8*)(y + (size_t)csrc[j] * 512 + l * 8);
#pragma unroll
        for (int c = 0; c < 8; ++c) acc[c] += (float)v0[c];
    }

    float4 bb0 = *(const float4*)(b1 + l * 8);
    float4 bb1 = *(const float4*)(b1 + l * 8 + 4);
    float4 w20 = *(const float4*)(W2 + l * 8);
    float4 w21 = *(const float4*)(W2 + l * 8 + 4);
    float bbv[8] = {bb0.x, bb0.y, bb0.z, bb0.w, bb1.x, bb1.y, bb1.z, bb1.w};
    float w2v[8] = {w20.x, w20.y, w20.z, w20.w, w21.x, w21.y, w21.z, w21.w};
    float p = 0.0f;
#pragma unroll
    for (int c = 0; c < 8; ++c) {
        float h = fmaxf(acc[c] * d1 + bbv[c], 0.0f);
        p += h * w2v[c];
    }
#pragma unroll
    for (int off = 32; off > 0; off >>= 1) p += __shfl_down(p, off);
    if (l == 0) z[n] = d1 * p;
}

// ---------------- layer-2 aggregation on prescaled scalars ----------------
__global__ void k_out(const float* __restrict__ z, const float* __restrict__ dis,
                      const int* __restrict__ rp, const int* __restrict__ csrc,
                      const float* __restrict__ b2, float* __restrict__ out, int N) {
    int n = blockIdx.x * blockDim.x + threadIdx.x;
    if (n >= N) return;
    float acc = z[n];
    int j = rp[n], jend = rp[n + 1];
    for (; j + 4 <= jend; j += 4) {
        float a0 = z[csrc[j]];
        float a1 = z[csrc[j + 1]];
        float a2 = z[csrc[j + 2]];
        float a3 = z[csrc[j + 3]];
        acc += (a0 + a1) + (a2 + a3);
    }
    for (; j < jend; ++j) acc += z[csrc[j]];
    out[n] = dis[n] * acc + b2[0];
}

extern "C" void kernel_launch(void* const* d_in, const int* in_sizes, int n_in,
                              void* d_out, int out_size, void* d_ws, size_t ws_size,
                              hipStream_t stream) {
    const float* x  = (const float*)d_in[0];
    const int*   ei = (const int*)d_in[1];
    const float* W1 = (const float*)d_in[2];
    const float* b1 = (const float*)d_in[3];
    const float* W2 = (const float*)d_in[4];
    const float* b2 = (const float*)d_in[5];
    float* out = (float*)d_out;

    const int N = in_sizes[0] / IN_CH;            // 50000
    const int E = in_sizes[1] / 2;                // 800000
    const int nbm = (N + 127) / 128;              // 391
    const int M2 = nbm * 128;                     // 50048
    const int NB = (N + SCAN_BLK - 1) / SCAN_BLK; // 49 (<= 64 for k_write)
    const int DEGB  = (E + 255) / 256;            // 3125 (merged1, 256 thr)
    const int FILLB = (E + 511) / 512;            // 1563 (merged2, 512 thr)
    const int nwg   = nbm * 2;                    // 782

    char* ws = (char*)d_ws;
    size_t off = 0;
    auto alloc = [&](size_t bytes) {
        char* p = ws + off;
        off += (bytes + 255) & ~(size_t)255;
        return p;
    };
    _Float16* y   = (_Float16*)alloc((size_t)M2 * 512 * sizeof(_Float16)); // 51.25 MB
    _Float16* W1t = (_Float16*)alloc((size_t)512 * 512 * sizeof(_Float16));
    int*   deg    = (int*)alloc((size_t)N * sizeof(int));
    float* dis    = (float*)alloc((size_t)N * sizeof(float));
    int*   rp     = (int*)alloc((size_t)(N + 1) * sizeof(int));
    int*   cursor = (int*)alloc((size_t)N * sizeof(int));
    int*   csrc   = (int*)alloc((size_t)E * sizeof(int));
    float* z      = (float*)alloc((size_t)N * sizeof(float));
    int*   bsum   = (int*)alloc((size_t)64 * sizeof(int));

    hipMemsetAsync(deg, 0, (size_t)N * sizeof(int), stream);

    k_merged1<<<256 + DEGB, 256, 0, stream>>>(W1, W1t, ei + E, deg, E, N);
    k_psum<<<NB, SCAN_BLK, 0, stream>>>(deg, bsum, N);
    k_write<<<NB, SCAN_BLK, 0, stream>>>(deg, bsum, rp, dis, cursor, N);
    k_merged2<<<nwg + FILLB, 512, 0, stream>>>(x, W1t, dis, y, N, nbm, nwg,
                                               ei, rp, cursor, csrc, E, N);
    k_agg<<<(N + 3) / 4, 256, 0, stream>>>(y, dis, rp, csrc, b1, W2, z, N);
    k_out<<<(N + 255) / 256, 256, 0, stream>>>(z, dis, rp, csrc, b2, out, N);
}